// Round 1
// baseline (858.171 us; speedup 1.0000x reference)
//
#include <hip/hip_runtime.h>

// Trilinear sampling of tsdf/weights volumes at M = B*H*N points.
// D = 256 fixed (reference). Outputs concatenated flat in d_out as float32:
//   [0,        M)   fusion_values
//   [M,      25M)   indices  (M,8,3) -- stored as float-valued integers
//   [25M,    33M)   weights  (M,8)
//   [33M,    34M)   fusion_weights

__global__ __launch_bounds__(256) void extractor_kernel(
    const float* __restrict__ points,
    const float* __restrict__ tsdf,
    const float* __restrict__ wvol,
    float* __restrict__ out,
    int M)
{
    const int m = blockIdx.x * 256 + threadIdx.x;
    if (m >= M) return;

    const size_t p3 = 3ull * (size_t)m;
    const float px = points[p3 + 0];
    const float py = points[p3 + 1];
    const float pz = points[p3 + 2];

    const float fx = floorf(px), fy = floorf(py), fz = floorf(pz);
    const int bx = (int)fx, by = (int)fy, bz = (int)fz;

    // center - p ; sign gives neighbor direction, |.| gives alpha
    const float dxc = fx + 0.5f - px;
    const float dyc = fy + 0.5f - py;
    const float dzc = fz + 0.5f - pz;

    const int nx = (dxc > 0.f) ? 1 : ((dxc < 0.f) ? -1 : 0);
    const int ny = (dyc > 0.f) ? 1 : ((dyc < 0.f) ? -1 : 0);
    const int nz = (dzc > 0.f) ? 1 : ((dzc < 0.f) ? -1 : 0);

    const float ax = fabsf(dxc), ay = fabsf(dyc), az = fabsf(dzc);
    const float axi = 1.f - ax, ayi = 1.f - ay, azi = 1.f - az;

    float fv = 0.f, fw = 0.f;
    float idxf[24];
    float wts[8];

#pragma unroll
    for (int c = 0; c < 8; ++c) {
        const int ox = (c >> 2) & 1;
        const int oy = (c >> 1) & 1;
        const int oz = c & 1;
        const int cx = bx + (ox ? nx : 0);
        const int cy = by + (oy ? ny : 0);
        const int cz = bz + (oz ? nz : 0);
        const float w = (ox ? ax : axi) * (oy ? ay : ayi) * (oz ? az : azi);
        const bool valid = ((unsigned)cx < 256u) & ((unsigned)cy < 256u) & ((unsigned)cz < 256u);
        const int ccx = min(max(cx, 0), 255);
        const int ccy = min(max(cy, 0), 255);
        const int ccz = min(max(cz, 0), 255);
        const int flat = (ccx << 16) | (ccy << 8) | ccz;
        const float vm = valid ? 1.f : 0.f;
        const float tv = tsdf[flat] * vm;
        const float wv = wvol[flat] * vm;
        fv += tv * w;
        fw += wv * w;
        idxf[c * 3 + 0] = (float)cx;
        idxf[c * 3 + 1] = (float)cy;
        idxf[c * 3 + 2] = (float)cz;
        wts[c] = w;
    }

    const size_t Ms = (size_t)M;
    out[m] = fv;
    out[33 * Ms + m] = fw;

    // indices block: 24 floats/thread, 96 B, 16B-aligned (M % 4 == 0)
    float4* __restrict__ oi = reinterpret_cast<float4*>(out + Ms + (size_t)m * 24);
    const float4* ii = reinterpret_cast<const float4*>(idxf);
#pragma unroll
    for (int i = 0; i < 6; ++i) oi[i] = ii[i];

    // weights block: 8 floats/thread, 32 B
    float4* __restrict__ ow = reinterpret_cast<float4*>(out + 25 * Ms + (size_t)m * 8);
    const float4* wi = reinterpret_cast<const float4*>(wts);
    ow[0] = wi[0];
    ow[1] = wi[1];
}

extern "C" void kernel_launch(void* const* d_in, const int* in_sizes, int n_in,
                              void* d_out, int out_size, void* d_ws, size_t ws_size,
                              hipStream_t stream) {
    const float* points = (const float*)d_in[0];
    const float* tsdf   = (const float*)d_in[1];
    const float* wvol   = (const float*)d_in[2];
    float* out = (float*)d_out;

    const int M = in_sizes[0] / 3;               // B*H*N
    const int blocks = (M + 255) / 256;
    extractor_kernel<<<blocks, 256, 0, stream>>>(points, tsdf, wvol, out, M);
}